// Round 5
// baseline (895.002 us; speedup 1.0000x reference)
//
#include <hip/hip_runtime.h>

// LGA (GANet Local Guided Aggregation), radius=2, K=5.
// in1: [N=4, C=32, H=384, W=768] f32
// in2: [N=4, 25,   H=384, W=768] f32 (per-pixel 5x5 taps, shared across C)
// out: [N, C, H, W] f32
//
// v4: back to the v2 structure (LDS zero-pad staging + double buffer +
// 1 barrier/channel; FETCH was ~ideal 228 MB), with the parallelism fixed.
// Counter-driven diagnosis of v0-v3:
//  - v2: pinned 100-reg weights -> ~184 regs/wave -> 2 waves/SIMD (occ 27%).
//  - v0: 64 VGPR but grid 1152 blocks = 4.5/CU -> only ~18 waves/CU (occ 33%).
//  - v3 (no LDS, no barriers): wave drift killed L1/L2 locality, FETCH 3.8x,
//    VALUBusy 4%. LDS staging is load-bearing for locality.
// Fixes in v4:
//  1. Channel-split grid x4 (8 ch/block, 4608 blocks = 18 blocks/CU of work).
//     Splits of a tile are adjacent post-swizzle -> same XCD -> redundant
//     weight reads are L2 hits.
//  2. Weights deliberately re-loaded per channel inside the loop (same
//     addresses every channel -> L1/L2 hits) instead of register-pinned;
//     __launch_bounds__(256,6) caps regs ~85 -> 6 waves/SIMD co-resident.

#define N_DIM 4
#define C_DIM 32
#define H_DIM 384
#define W_DIM 768
#define HW (H_DIM * W_DIM)
#define TH 4          // output rows per block (4 waves)
#define TW 256        // output cols per block (64 lanes x 4 pixels)
#define CSPLIT 4
#define CPB (C_DIM / CSPLIT)              // 8 channels per block
#define LROWS (TH + 4)
#define LW 260        // LDS row stride in floats: cols [w0-2, w0+258)
#define CHUNKS (LROWS * 65)               // 520 float4 chunks per buffer
#define NTILE ((W_DIM / TW) * (H_DIM / TH) * N_DIM)   // 3*96*4 = 1152
#define NWG (NTILE * CSPLIT)                          // 4608 (%8==0)

__global__ __launch_bounds__(256, 6)
void lga_kernel(const float* __restrict__ in1,
                const float* __restrict__ in2,
                float* __restrict__ out) {
    __shared__ float lds[2][LROWS * LW];   // 2 x 8.32 KB

    // XCD-bijective chunked swizzle; channel-split decoded FASTEST so the
    // 4 splits of one tile sit at T=4t..4t+3 (same XCD chunk, dispatched
    // within 24 blocks of each other -> weight reads dedupe in L2).
    const int b = blockIdx.x;
    const int T = (b & 7) * (NWG / 8) + (b >> 3);
    const int cs = T & 3;
    const int t  = T >> 2;
    const int bx = t % 3;
    const int by = (t / 3) % (H_DIM / TH);
    const int n  = t / (3 * (H_DIM / TH));
    const int c0 = cs * CPB;

    const int tid = threadIdx.x;
    const int tx  = tid & 63;           // lane
    const int ty  = tid >> 6;           // wave = output row in tile
    const int w0  = bx * TW;
    const int h0  = by * TH;
    const int h   = h0 + ty;            // output row
    const int wb  = w0 + 4 * tx;        // first of 4 output cols

    // weight base: 25 taps at stride HW, re-read per channel (L1/L2-hot)
    const float* w_src = in2 + ((size_t)n * 25) * HW + (size_t)h * W_DIM + wb;

    // ---- staging descriptors: chunks tid, tid+256, tid+512 (v2 scheme) ----
    int  soff[3];   // gh*W + g (valid when rok)
    int  ldst[3];   // LDS float offset
    int  gcol[3];   // global col of chunk start (== 2 mod 4)
    bool fast[3];   // fully interior chunk
    bool rok[3];    // row in range
    bool act[3];    // chunk exists (3rd: tid < 8)
#pragma unroll
    for (int k = 0; k < 3; ++k) {
        const int idx = tid + 256 * k;
        act[k] = (k < 2) || (tid < CHUNKS - 512);
        const int row = idx / 65;
        const int c4  = idx - row * 65;
        const int gh  = h0 - 2 + row;
        const int g   = w0 - 2 + 4 * c4;
        rok[k]  = (unsigned)gh < H_DIM;
        gcol[k] = g;
        fast[k] = rok[k] && (g >= 0) && (g + 3 < W_DIM);
        soff[k] = (rok[k] ? gh : 0) * W_DIM + g;
        ldst[k] = row * LW + 4 * c4;
    }

    auto load_chunk = [&](const float* src, int k) -> float4 {
        float4 v;
        if (fast[k]) {
            const float* p = src + soff[k];          // 8B aligned (g == 2 mod 4)
            const float2 a = *(const float2*)p;
            const float2 b2 = *(const float2*)(p + 2);
            v = make_float4(a.x, a.y, b2.x, b2.y);
        } else {
            const int g = gcol[k];
            const float* prow = src + (soff[k] - g); // row base (valid iff rok)
            v.x = (rok[k] && (unsigned)(g + 0) < W_DIM) ? prow[g + 0] : 0.f;
            v.y = (rok[k] && (unsigned)(g + 1) < W_DIM) ? prow[g + 1] : 0.f;
            v.z = (rok[k] && (unsigned)(g + 2) < W_DIM) ? prow[g + 2] : 0.f;
            v.w = (rok[k] && (unsigned)(g + 3) < W_DIM) ? prow[g + 3] : 0.f;
        }
        return v;
    };

    const float* src0 = in1 + (size_t)n * C_DIM * HW + (size_t)c0 * HW;
    float*       dst  = out + (size_t)n * C_DIM * HW + (size_t)c0 * HW
                            + (size_t)h * W_DIM + wb;

    // ---- prologue: stage channel c0 into lds[0] ----
    {
        float4 v0 = load_chunk(src0, 0);
        float4 v1 = load_chunk(src0, 1);
        float4 v2 = make_float4(0.f, 0.f, 0.f, 0.f);
        if (act[2]) v2 = load_chunk(src0, 2);
        *(float4*)&lds[0][ldst[0]] = v0;
        *(float4*)&lds[0][ldst[1]] = v1;
        if (act[2]) *(float4*)&lds[0][ldst[2]] = v2;
    }
    __syncthreads();

    for (int cc = 0; cc < CPB; ++cc) {
        const int  cur  = cc & 1;
        const bool more = (cc + 1 < CPB);      // uniform across block

        // (1) issue next channel's global loads (hide under compute)
        float4 n0, n1, n2 = make_float4(0.f, 0.f, 0.f, 0.f);
        if (more) {
            const float* srcn = src0 + (size_t)(cc + 1) * HW;
            n0 = load_chunk(srcn, 0);
            n1 = load_chunk(srcn, 1);
            if (act[2]) n2 = load_chunk(srcn, 2);
        }

        // (2) compute 4 pixels from lds[cur]; weights re-read per channel
        float acc0 = 0.f, acc1 = 0.f, acc2 = 0.f, acc3 = 0.f;
        const float* lbase = &lds[cur][0];
#pragma unroll
        for (int i = 0; i < 5; ++i) {
            const float* lrow = lbase + (ty + i) * LW + 4 * tx;  // col wb-2
            const float4 A = *(const float4*)lrow;               // win[0..3]
            const float4 B = *(const float4*)(lrow + 4);         // win[4..7]
            const float win[8] = {A.x, A.y, A.z, A.w, B.x, B.y, B.z, B.w};
            float4 wv[5];
#pragma unroll
            for (int j = 0; j < 5; ++j)
                wv[j] = *(const float4*)(w_src + (size_t)(5 * i + j) * HW);
#pragma unroll
            for (int j = 0; j < 5; ++j) {
                acc0 += wv[j].x * win[j + 0];
                acc1 += wv[j].y * win[j + 1];
                acc2 += wv[j].z * win[j + 2];
                acc3 += wv[j].w * win[j + 3];
            }
        }

        *(float4*)(dst + (size_t)cc * HW) = make_float4(acc0, acc1, acc2, acc3);

        // (3) write next tile into the other buffer; one barrier per channel
        if (more) {
            float* dbuf = &lds[cur ^ 1][0];
            *(float4*)&dbuf[ldst[0]] = n0;
            *(float4*)&dbuf[ldst[1]] = n1;
            if (act[2]) *(float4*)&dbuf[ldst[2]] = n2;
            __syncthreads();
        }
    }
}

extern "C" void kernel_launch(void* const* d_in, const int* in_sizes, int n_in,
                              void* d_out, int out_size, void* d_ws, size_t ws_size,
                              hipStream_t stream) {
    const float* in1 = (const float*)d_in[0];
    const float* in2 = (const float*)d_in[1];
    float* out = (float*)d_out;
    lga_kernel<<<dim3(NWG), 256, 0, stream>>>(in1, in2, out);
}